// Round 1
// 114.034 us; speedup vs baseline: 1.0443x; 1.0443x over previous
//
#include <hip/hip_runtime.h>

#define B 2
#define S 2048
#define A 16
#define H 1024
#define NH 16
#define HD 64
#define CH 4    // j-chunks per head in kQW
#define KT 8    // k-rows per kB block (512 thr -> 1 k-row/wave; 2 blocks/CU)
#define QC 16   // query rows per kD block
#define KC 1024 // k columns per kD block
#define EOFF 20.0f  // softmax shift: exp(s-EOFF); scores ~N(0,1), no overflow risk

typedef float f32x4 __attribute__((ext_vector_type(4)));

// ---- kQW: fused masked-mean + Q projection + effective K-weights ----------
// grid = B*NH*CH = 128 blocks. Each block redundantly computes agg[b] and
// q[b,h,:] (cheap, L2-hot), then 256 weff outputs with coalesced Wk reads.
// Block 0 also zero-inits dsum (stream order guarantees visibility to kB).
__global__ __launch_bounds__(256) void kQW(const float* __restrict__ h2,
                                           const int* __restrict__ amask,
                                           const float* __restrict__ Wq,
                                           const float* __restrict__ Wk,
                                           float* __restrict__ weff,
                                           float* __restrict__ dsum) {
    __shared__ float agg[H];
    __shared__ float qs[HD];
    int blk = blockIdx.x;
    int c = blk & (CH - 1);
    int bh = blk / CH;
    int b = bh >> 4, h = bh & 15;
    int tid = threadIdx.x;

    if (blk == 0 && tid < B * NH) dsum[tid] = 0.f;  // denom accumulators

    // masked mean over aspects: thread owns 4 contiguous columns
    {
        const float4* h2b = (const float4*)(h2 + (size_t)b * A * H);
        float4 sum = make_float4(0.f, 0.f, 0.f, 0.f);
        int cnt = 0;
#pragma unroll
        for (int a = 0; a < A; a++) {
            if (amask[b * A + a]) {
                float4 v = h2b[a * (H / 4) + tid];
                sum.x += v.x; sum.y += v.y; sum.z += v.z; sum.w += v.w; cnt++;
            }
        }
        float inv = 1.0f / (float)(cnt > 0 ? cnt : 1);
        ((float4*)agg)[tid] = make_float4(sum.x * inv, sum.y * inv, sum.z * inv, sum.w * inv);
    }
    __syncthreads();

    // q for this head: 64 wave-dots (4 waves x 16)
    int wave = tid >> 6, lane = tid & 63;
    const float4* ag = (const float4*)agg;
    for (int d = wave * 16; d < wave * 16 + 16; d++) {
        const float4* wr = (const float4*)(Wq + (size_t)(h * HD + d) * H);
        float acc = 0.f;
#pragma unroll
        for (int t = 0; t < 4; t++) {
            int j4 = lane + 64 * t;
            float4 a4 = ag[j4], w4 = wr[j4];
            acc += a4.x * w4.x + a4.y * w4.y + a4.z * w4.z + a4.w * w4.w;
        }
        for (int off = 32; off > 0; off >>= 1) acc += __shfl_down(acc, off);
        if (lane == 0) qs[d] = acc;
    }
    __syncthreads();

    // weff chunk: one thread per output column j; Wk reads coalesced
    int j = c * 256 + tid;
    float acc = 0.f;
#pragma unroll 8
    for (int d = 0; d < HD; d++) acc += qs[d] * Wk[(size_t)(h * HD + d) * H + j];
    weff[((size_t)b * NH + h) * H + j] = acc * 0.125f;  // scale = 64^-0.5
}

// ---- kB: e[b,h,k] = mask ? exp(weff[b,h,:].h1[b,k,:] - EOFF) : 0 ----------
// plus per-(b,h) partial denominators via one coalesced atomicAdd per block.
// All 16 heads staged (64 KB LDS) -> h1 read exactly once (16 MB total).
// grid = B*(S/KT) = 512 blocks, 512 threads, 2 blocks/CU.
__global__ __launch_bounds__(512) void kB(const float* __restrict__ h1,
                                          const float* __restrict__ weff,
                                          const int* __restrict__ smask,
                                          float* __restrict__ e,
                                          float* __restrict__ dsum) {
    __shared__ float4 lw[NH * H / 4];  // 64 KB (exactly the per-block limit)
    int blk = blockIdx.x;
    int kt = blk % (S / KT);
    int b  = blk / (S / KT);
    const float4* wsrc = (const float4*)(weff + (size_t)b * NH * H);
#pragma unroll
    for (int i = threadIdx.x; i < NH * H / 4; i += 512) lw[i] = wsrc[i];
    __syncthreads();

    int wave = threadIdx.x >> 6, lane = threadIdx.x & 63;
    int k = kt * KT + wave;              // one k-row per wave
    int mk = smask[b * S + k];           // wave-uniform -> scalar load
    const float4* row = (const float4*)(h1 + ((size_t)b * S + k) * H);
    float4 x[4];
#pragma unroll
    for (int t = 0; t < 4; t++) x[t] = row[lane + 64 * t];

    float dl[NH];  // lane0-only head denominator contributions
#pragma unroll
    for (int hh = 0; hh < NH; hh++) {
        float acc = 0.f;
#pragma unroll
        for (int t = 0; t < 4; t++) {
            float4 wv = lw[hh * (H / 4) + lane + 64 * t];
            acc += wv.x * x[t].x + wv.y * x[t].y + wv.z * x[t].z + wv.w * x[t].w;
        }
        for (int off = 32; off > 0; off >>= 1) acc += __shfl_down(acc, off);
        if (lane == 0) {
            float ev = mk ? expf(acc - EOFF) : 0.f;
            e[((size_t)b * NH + hh) * S + k] = ev;
            dl[hh] = ev;
        }
    }

    // block-level denominator reduction; reuse lw as scratch (reads are done)
    __syncthreads();
    float* dred = (float*)lw;  // [8 waves][NH]
    if (lane == 0) {
#pragma unroll
        for (int hh = 0; hh < NH; hh++) dred[wave * NH + hh] = dl[hh];
    }
    __syncthreads();
    if (threadIdx.x < NH) {
        float sum = 0.f;
#pragma unroll
        for (int w = 0; w < KT; w++) sum += dred[w * NH + threadIdx.x];
        atomicAdd(&dsum[b * NH + threadIdx.x], sum);
    }
}

// ---- kD: head-mean weight + broadcast over query rows ---------------------
// grid = B*(S/KC)*(S/QC) = 512 blocks. Each thread computes its 4 w-values
// from L2-resident e (no expf, no mask - already folded into e), then
// streams QC=16 identical output rows with nontemporal stores.
__global__ __launch_bounds__(256) void kD(const float* __restrict__ e,
                                          const float* __restrict__ dsum,
                                          float* __restrict__ out) {
    int blk = blockIdx.x;
    int b  = blk >> 8;                  // 256 blocks per batch
    int r  = blk & 255;
    int kc = r >> 7;                    // 0..1
    int q0 = (r & 127) * QC;
    int tid = threadIdx.x;

    // per-head inverse denominators (block-uniform -> scalar loads)
    float ih[NH];
#pragma unroll
    for (int h = 0; h < NH; h++) ih[h] = 1.0f / dsum[b * NH + h];

    // w chunk: one float4 per thread
    int kk = kc * KC + tid * 4;
    float4 val = make_float4(0.f, 0.f, 0.f, 0.f);
#pragma unroll
    for (int h = 0; h < NH; h++) {
        float4 ev = *(const float4*)(e + ((size_t)b * NH + h) * S + kk);
        val.x += ev.x * ih[h];
        val.y += ev.y * ih[h];
        val.z += ev.z * ih[h];
        val.w += ev.w * ih[h];
    }
    const float inh = 1.0f / NH;
    f32x4 v = {val.x * inh, val.y * inh, val.z * inh, val.w * inh};

    // broadcast: QC identical rows, 4 KB contiguous per row per block
#pragma unroll
    for (int qi = 0; qi < QC; qi++) {
        f32x4* dst = (f32x4*)(out + ((size_t)(b * S + q0 + qi)) * S + kc * KC);
        __builtin_nontemporal_store(v, dst + tid);
    }
}

extern "C" void kernel_launch(void* const* d_in, const int* in_sizes, int n_in,
                              void* d_out, int out_size, void* d_ws, size_t ws_size,
                              hipStream_t stream) {
    const float* h1    = (const float*)d_in[0];   // [B,S,H]
    const float* h2    = (const float*)d_in[1];   // [B,A,H]
    const int*   smask = (const int*)d_in[2];     // [B,S]
    const int*   amask = (const int*)d_in[3];     // [B,A]
    const float* Wq    = (const float*)d_in[4];   // [H,H]
    const float* Wk    = (const float*)d_in[5];   // [H,H]
    float* out = (float*)d_out;                   // [B,S,S]
    float* ws  = (float*)d_ws;

    float* weff = ws;            // B*NH*H  = 32768 floats
    float* e    = ws + 32768;    // B*NH*S  = 65536 floats (masked exp scores)
    float* dsum = ws + 98304;    // B*NH    = 32 floats

    kQW<<<B * NH * CH, 256, 0, stream>>>(h2, amask, Wq, Wk, weff, dsum);
    kB <<<B * (S / KT), 512, 0, stream>>>(h1, weff, smask, e, dsum);
    kD <<<B * (S / KC) * (S / QC), 256, 0, stream>>>(e, dsum, out);
}

// Round 2
// 112.502 us; speedup vs baseline: 1.0585x; 1.0136x over previous
//
#include <hip/hip_runtime.h>

#define B 2
#define S 2048
#define A 16
#define H 1024
#define NH 16
#define HD 64
#define CH 4    // j-chunks per head in kQW
#define KT 8    // k-rows per kB block (512 thr -> 1 k-row/wave; 2 blocks/CU)
#define QC 16   // query rows per kD block
#define KC 1024 // k columns per kD block
#define EOFF 20.0f  // softmax shift: exp(s-EOFF); scores ~N(0,1), no overflow risk

typedef float f32x4 __attribute__((ext_vector_type(4)));

// ---- kQW: fused masked-mean + Q projection + effective K-weights ----------
// grid = B*NH*CH = 128 blocks. Each block redundantly computes agg[b] and
// q[b,h,:] (cheap), then 256 weff outputs with coalesced Wk reads.
// Block-index layout: bh in LOW 5 bits, chunk c in HIGH bits. The 4 chunks
// of one (b,h) are blocks {bh, bh+32, bh+64, bh+96} == bh (mod 8) -> same
// XCD; batches b=0/1 of a head (bh, bh+16) too. Their identical Wq-row /
// Wk-row reads merge in that XCD's L2, so Wq+Wk come from HBM once (8 MB)
// instead of ~4x with consecutive-chunk ordering.
// Block 0 also zero-inits dsum (stream order guarantees visibility to kB).
__global__ __launch_bounds__(256) void kQW(const float* __restrict__ h2,
                                           const int* __restrict__ amask,
                                           const float* __restrict__ Wq,
                                           const float* __restrict__ Wk,
                                           float* __restrict__ weff,
                                           float* __restrict__ dsum) {
    __shared__ float agg[H];
    __shared__ float qs[HD];
    int blk = blockIdx.x;
    int bh = blk & 31;      // low bits: same (b,h) group shares an XCD
    int c  = blk >> 5;      // chunk index in high bits (stride 32 == 0 mod 8)
    int b = bh >> 4, h = bh & 15;
    int tid = threadIdx.x;

    if (blk == 0 && tid < B * NH) dsum[tid] = 0.f;  // denom accumulators

    // masked mean over aspects: thread owns 4 contiguous columns
    {
        const float4* h2b = (const float4*)(h2 + (size_t)b * A * H);
        float4 sum = make_float4(0.f, 0.f, 0.f, 0.f);
        int cnt = 0;
#pragma unroll
        for (int a = 0; a < A; a++) {
            if (amask[b * A + a]) {
                float4 v = h2b[a * (H / 4) + tid];
                sum.x += v.x; sum.y += v.y; sum.z += v.z; sum.w += v.w; cnt++;
            }
        }
        float inv = 1.0f / (float)(cnt > 0 ? cnt : 1);
        ((float4*)agg)[tid] = make_float4(sum.x * inv, sum.y * inv, sum.z * inv, sum.w * inv);
    }
    __syncthreads();

    // q for this head: 64 wave-dots (4 waves x 16)
    int wave = tid >> 6, lane = tid & 63;
    const float4* ag = (const float4*)agg;
    for (int d = wave * 16; d < wave * 16 + 16; d++) {
        const float4* wr = (const float4*)(Wq + (size_t)(h * HD + d) * H);
        float acc = 0.f;
#pragma unroll
        for (int t = 0; t < 4; t++) {
            int j4 = lane + 64 * t;
            float4 a4 = ag[j4], w4 = wr[j4];
            acc += a4.x * w4.x + a4.y * w4.y + a4.z * w4.z + a4.w * w4.w;
        }
        for (int off = 32; off > 0; off >>= 1) acc += __shfl_down(acc, off);
        if (lane == 0) qs[d] = acc;
    }
    __syncthreads();

    // weff chunk: one thread per output column j; Wk reads coalesced
    int j = c * 256 + tid;
    float acc = 0.f;
#pragma unroll 8
    for (int d = 0; d < HD; d++) acc += qs[d] * Wk[(size_t)(h * HD + d) * H + j];
    weff[((size_t)b * NH + h) * H + j] = acc * 0.125f;  // scale = 64^-0.5
}

// ---- kB: e[b,h,k] = mask ? exp(weff[b,h,:].h1[b,k,:] - EOFF) : 0 ----------
// plus per-(b,h) partial denominators via one coalesced atomicAdd per block.
// All 16 heads staged (64 KB LDS) -> h1 read exactly once (16 MB total).
// grid = B*(S/KT) = 512 blocks, 512 threads, 2 blocks/CU.
__global__ __launch_bounds__(512) void kB(const float* __restrict__ h1,
                                          const float* __restrict__ weff,
                                          const int* __restrict__ smask,
                                          float* __restrict__ e,
                                          float* __restrict__ dsum) {
    __shared__ float4 lw[NH * H / 4];  // 64 KB (exactly the per-block limit)
    int blk = blockIdx.x;
    int kt = blk % (S / KT);
    int b  = blk / (S / KT);
    const float4* wsrc = (const float4*)(weff + (size_t)b * NH * H);
#pragma unroll
    for (int i = threadIdx.x; i < NH * H / 4; i += 512) lw[i] = wsrc[i];
    __syncthreads();

    int wave = threadIdx.x >> 6, lane = threadIdx.x & 63;
    int k = kt * KT + wave;              // one k-row per wave
    int mk = smask[b * S + k];           // wave-uniform -> scalar load
    const float4* row = (const float4*)(h1 + ((size_t)b * S + k) * H);
    float4 x[4];
#pragma unroll
    for (int t = 0; t < 4; t++) x[t] = row[lane + 64 * t];

    float dl[NH];  // lane0-only head denominator contributions
#pragma unroll
    for (int hh = 0; hh < NH; hh++) {
        float acc = 0.f;
#pragma unroll
        for (int t = 0; t < 4; t++) {
            float4 wv = lw[hh * (H / 4) + lane + 64 * t];
            acc += wv.x * x[t].x + wv.y * x[t].y + wv.z * x[t].z + wv.w * x[t].w;
        }
        for (int off = 32; off > 0; off >>= 1) acc += __shfl_down(acc, off);
        if (lane == 0) {
            float ev = mk ? expf(acc - EOFF) : 0.f;
            e[((size_t)b * NH + hh) * S + k] = ev;
            dl[hh] = ev;
        }
    }

    // block-level denominator reduction; reuse lw as scratch (reads are done)
    __syncthreads();
    float* dred = (float*)lw;  // [8 waves][NH]
    if (lane == 0) {
#pragma unroll
        for (int hh = 0; hh < NH; hh++) dred[wave * NH + hh] = dl[hh];
    }
    __syncthreads();
    if (threadIdx.x < NH) {
        float sum = 0.f;
#pragma unroll
        for (int w = 0; w < KT; w++) sum += dred[w * NH + threadIdx.x];
        atomicAdd(&dsum[b * NH + threadIdx.x], sum);
    }
}

// ---- kD: head-mean weight + broadcast over query rows ---------------------
// grid = B*(S/KC)*(S/QC) = 512 blocks. Each thread computes its 4 w-values
// from L2-resident e (no expf, no mask - already folded into e), then
// streams QC=16 identical output rows with nontemporal stores.
__global__ __launch_bounds__(256) void kD(const float* __restrict__ e,
                                          const float* __restrict__ dsum,
                                          float* __restrict__ out) {
    int blk = blockIdx.x;
    int b  = blk >> 8;                  // 256 blocks per batch
    int r  = blk & 255;
    int kc = r >> 7;                    // 0..1
    int q0 = (r & 127) * QC;
    int tid = threadIdx.x;

    // per-head inverse denominators (block-uniform -> scalar loads)
    float ih[NH];
#pragma unroll
    for (int h = 0; h < NH; h++) ih[h] = 1.0f / dsum[b * NH + h];

    // w chunk: one float4 per thread
    int kk = kc * KC + tid * 4;
    float4 val = make_float4(0.f, 0.f, 0.f, 0.f);
#pragma unroll
    for (int h = 0; h < NH; h++) {
        float4 ev = *(const float4*)(e + ((size_t)b * NH + h) * S + kk);
        val.x += ev.x * ih[h];
        val.y += ev.y * ih[h];
        val.z += ev.z * ih[h];
        val.w += ev.w * ih[h];
    }
    const float inh = 1.0f / NH;
    f32x4 v = {val.x * inh, val.y * inh, val.z * inh, val.w * inh};

    // broadcast: QC identical rows, 4 KB contiguous per row per block
#pragma unroll
    for (int qi = 0; qi < QC; qi++) {
        f32x4* dst = (f32x4*)(out + ((size_t)(b * S + q0 + qi)) * S + kc * KC);
        __builtin_nontemporal_store(v, dst + tid);
    }
}

extern "C" void kernel_launch(void* const* d_in, const int* in_sizes, int n_in,
                              void* d_out, int out_size, void* d_ws, size_t ws_size,
                              hipStream_t stream) {
    const float* h1    = (const float*)d_in[0];   // [B,S,H]
    const float* h2    = (const float*)d_in[1];   // [B,A,H]
    const int*   smask = (const int*)d_in[2];     // [B,S]
    const int*   amask = (const int*)d_in[3];     // [B,A]
    const float* Wq    = (const float*)d_in[4];   // [H,H]
    const float* Wk    = (const float*)d_in[5];   // [H,H]
    float* out = (float*)d_out;                   // [B,S,S]
    float* ws  = (float*)d_ws;

    float* weff = ws;            // B*NH*H  = 32768 floats
    float* e    = ws + 32768;    // B*NH*S  = 65536 floats (masked exp scores)
    float* dsum = ws + 98304;    // B*NH    = 32 floats

    kQW<<<B * NH * CH, 256, 0, stream>>>(h2, amask, Wq, Wk, weff, dsum);
    kB <<<B * (S / KT), 512, 0, stream>>>(h1, weff, smask, e, dsum);
    kD <<<B * (S / KC) * (S / QC), 256, 0, stream>>>(e, dsum, out);
}

// Round 4
// 108.471 us; speedup vs baseline: 1.0979x; 1.0372x over previous
//
#include <hip/hip_runtime.h>

#define B 2
#define S 2048
#define A 16
#define H 1024
#define NH 16
#define HD 64
#define CH 4    // j-chunks per head in kQW (256 cols each)
#define KT 8    // k-rows per kB block (512 thr -> 1 k-row/wave; 2 blocks/CU)
#define QC 16   // query rows per kD block
#define KC 1024 // k columns per kD block
#define EOFF 20.0f  // softmax shift: exp(s-EOFF); scores ~N(0,1), no overflow risk

typedef float f32x4 __attribute__((ext_vector_type(4)));

// ---- kQW: fused masked-mean + Q projection + effective K-weights ----------
// grid = B*NH*CH = 128 blocks x 512 threads. Block-index layout: bh in LOW
// 5 bits, chunk c in HIGH bits -> the 4 chunks of one (b,h) and both batches
// of a head land on the same XCD, so their identical Wq/Wk-row reads merge
// in that XCD's L2 (Wq+Wk fetched from HBM ~once, 8 MB).
// 512 threads: q-dots 8 waves x 8 (was 4x16); weff d-loop split in two
// 32-d halves across tid<256 / tid>=256 (two Wk rows in flight).
// Block 0 also zero-inits dsum (stream order guarantees visibility to kB).
__global__ __launch_bounds__(512) void kQW(const float* __restrict__ h2,
                                           const int* __restrict__ amask,
                                           const float* __restrict__ Wq,
                                           const float* __restrict__ Wk,
                                           float* __restrict__ weff,
                                           float* __restrict__ dsum) {
    __shared__ float agg[H];    // 4 KB
    __shared__ float qs[HD];    // 256 B
    __shared__ float part[256]; // 1 KB: weff half-combine
    int blk = blockIdx.x;
    int bh = blk & 31;      // low bits: same (b,h) group shares an XCD
    int c  = blk >> 5;      // chunk index in high bits (stride 32 == 0 mod 8)
    int b = bh >> 4, h = bh & 15;
    int tid = threadIdx.x;
    int wave = tid >> 6, lane = tid & 63;

    if (blk == 0 && tid < B * NH) dsum[tid] = 0.f;  // denom accumulators

    // masked mean over aspects: 512 threads x 2 contiguous columns
    {
        const float2* h2b = (const float2*)(h2 + (size_t)b * A * H);
        float2 sum = make_float2(0.f, 0.f);
        int cnt = 0;
#pragma unroll
        for (int a = 0; a < A; a++) {
            if (amask[b * A + a]) {
                float2 v = h2b[a * (H / 2) + tid];
                sum.x += v.x; sum.y += v.y; cnt++;
            }
        }
        float inv = 1.0f / (float)(cnt > 0 ? cnt : 1);
        ((float2*)agg)[tid] = make_float2(sum.x * inv, sum.y * inv);
    }
    __syncthreads();

    // q for this head: 64 wave-dots, 8 waves x 8 sequential each
    const float4* ag = (const float4*)agg;
#pragma unroll
    for (int r = 0; r < 8; r++) {
        int d = wave * 8 + r;
        const float4* wr = (const float4*)(Wq + (size_t)(h * HD + d) * H);
        float acc = 0.f;
#pragma unroll
        for (int t = 0; t < 4; t++) {
            int j4 = lane + 64 * t;
            float4 a4 = ag[j4], w4 = wr[j4];
            acc += a4.x * w4.x + a4.y * w4.y + a4.z * w4.z + a4.w * w4.w;
        }
        for (int off = 32; off > 0; off >>= 1) acc += __shfl_down(acc, off);
        if (lane == 0) qs[d] = acc;
    }
    __syncthreads();

    // weff chunk: column j owned by thread pair (tid, tid+256); each half
    // covers 32 d's; Wk reads coalesced across the 256 lanes of each half.
    int jj = tid & 255;
    int j = c * 256 + jj;
    int dh = (tid >> 8) * 32;
    float acc = 0.f;
#pragma unroll 8
    for (int d = dh; d < dh + 32; d++)
        acc += qs[d] * Wk[(size_t)(h * HD + d) * H + j];
    if (tid >= 256) part[jj] = acc;
    __syncthreads();
    if (tid < 256)
        weff[((size_t)b * NH + h) * H + j] = (acc + part[jj]) * 0.125f;  // scale = 64^-0.5
}

// ---- kB: e[b,h,k] = mask ? exp(weff[b,h,:].h1[b,k,:] - EOFF) : 0 ----------
// plus per-(b,h) partial denominators via one coalesced atomicAdd per block.
// All 16 heads staged (64 KB LDS) -> h1 read exactly once (16 MB total).
// grid = B*(S/KT) = 512 blocks, 512 threads, 2 blocks/CU.
__global__ __launch_bounds__(512) void kB(const float* __restrict__ h1,
                                          const float* __restrict__ weff,
                                          const int* __restrict__ smask,
                                          float* __restrict__ e,
                                          float* __restrict__ dsum) {
    __shared__ float4 lw[NH * H / 4];  // 64 KB (exactly the per-block limit)
    int blk = blockIdx.x;
    int kt = blk % (S / KT);
    int b  = blk / (S / KT);
    const float4* wsrc = (const float4*)(weff + (size_t)b * NH * H);
#pragma unroll
    for (int i = threadIdx.x; i < NH * H / 4; i += 512) lw[i] = wsrc[i];
    __syncthreads();

    int wave = threadIdx.x >> 6, lane = threadIdx.x & 63;
    int k = kt * KT + wave;              // one k-row per wave
    int mk = smask[b * S + k];           // wave-uniform -> scalar load
    const float4* row = (const float4*)(h1 + ((size_t)b * S + k) * H);
    float4 x[4];
#pragma unroll
    for (int t = 0; t < 4; t++) x[t] = row[lane + 64 * t];

    float dl[NH];  // lane0-only head denominator contributions
#pragma unroll
    for (int hh = 0; hh < NH; hh++) {
        float acc = 0.f;
#pragma unroll
        for (int t = 0; t < 4; t++) {
            float4 wv = lw[hh * (H / 4) + lane + 64 * t];
            acc += wv.x * x[t].x + wv.y * x[t].y + wv.z * x[t].z + wv.w * x[t].w;
        }
        for (int off = 32; off > 0; off >>= 1) acc += __shfl_down(acc, off);
        if (lane == 0) {
            float ev = mk ? expf(acc - EOFF) : 0.f;
            e[((size_t)b * NH + hh) * S + k] = ev;
            dl[hh] = ev;
        }
    }

    // block-level denominator reduction; reuse lw as scratch (reads are done)
    __syncthreads();
    float* dred = (float*)lw;  // [8 waves][NH]
    if (lane == 0) {
#pragma unroll
        for (int hh = 0; hh < NH; hh++) dred[wave * NH + hh] = dl[hh];
    }
    __syncthreads();
    if (threadIdx.x < NH) {
        float sum = 0.f;
#pragma unroll
        for (int w = 0; w < KT; w++) sum += dred[w * NH + threadIdx.x];
        atomicAdd(&dsum[b * NH + threadIdx.x], sum);
    }
}

// ---- kD: head-mean weight + broadcast over query rows ---------------------
// grid = B*(S/KC)*(S/QC) = 512 blocks. Each thread computes its 4 w-values
// from L2-resident e (no expf, no mask - already folded into e), then
// streams QC=16 identical output rows with nontemporal stores.
__global__ __launch_bounds__(256) void kD(const float* __restrict__ e,
                                          const float* __restrict__ dsum,
                                          float* __restrict__ out) {
    int blk = blockIdx.x;
    int b  = blk >> 8;                  // 256 blocks per batch
    int r  = blk & 255;
    int kc = r >> 7;                    // 0..1
    int q0 = (r & 127) * QC;
    int tid = threadIdx.x;

    // per-head inverse denominators (block-uniform -> scalar loads)
    float ih[NH];
#pragma unroll
    for (int h = 0; h < NH; h++) ih[h] = 1.0f / dsum[b * NH + h];

    // w chunk: one float4 per thread
    int kk = kc * KC + tid * 4;
    float4 val = make_float4(0.f, 0.f, 0.f, 0.f);
#pragma unroll
    for (int h = 0; h < NH; h++) {
        float4 ev = *(const float4*)(e + ((size_t)b * NH + h) * S + kk);
        val.x += ev.x * ih[h];
        val.y += ev.y * ih[h];
        val.z += ev.z * ih[h];
        val.w += ev.w * ih[h];
    }
    const float inh = 1.0f / NH;
    f32x4 v = {val.x * inh, val.y * inh, val.z * inh, val.w * inh};

    // broadcast: QC identical rows, 4 KB contiguous per row per block
#pragma unroll
    for (int qi = 0; qi < QC; qi++) {
        f32x4* dst = (f32x4*)(out + ((size_t)(b * S + q0 + qi)) * S + kc * KC);
        __builtin_nontemporal_store(v, dst + tid);
    }
}

extern "C" void kernel_launch(void* const* d_in, const int* in_sizes, int n_in,
                              void* d_out, int out_size, void* d_ws, size_t ws_size,
                              hipStream_t stream) {
    const float* h1    = (const float*)d_in[0];   // [B,S,H]
    const float* h2    = (const float*)d_in[1];   // [B,A,H]
    const int*   smask = (const int*)d_in[2];     // [B,S]
    const int*   amask = (const int*)d_in[3];     // [B,A]
    const float* Wq    = (const float*)d_in[4];   // [H,H]
    const float* Wk    = (const float*)d_in[5];   // [H,H]
    float* out = (float*)d_out;                   // [B,S,S]
    float* ws  = (float*)d_ws;

    float* weff = ws;            // B*NH*H  = 32768 floats
    float* e    = ws + 32768;    // B*NH*S  = 65536 floats (masked exp scores)
    float* dsum = ws + 98304;    // B*NH    = 32 floats

    kQW<<<B * NH * CH, 512, 0, stream>>>(h2, amask, Wq, Wk, weff, dsum);
    kB <<<B * (S / KT), 512, 0, stream>>>(h1, weff, smask, e, dsum);
    kD <<<B * (S / KC) * (S / QC), 256, 0, stream>>>(e, dsum, out);
}